// Round 10
// baseline (114.249 us; speedup 1.0000x reference)
//
#include <hip/hip_runtime.h>

#define B_   64
#define H_   128
#define W_   2048
#define HW_  (H_ * W_)        // 262144
#define OH_  128
#define OW_  2048

typedef float nfloat4 __attribute__((ext_vector_type(4)));

// OpenBLAS sgemm emulation — SkylakeX params (VERIFIED bit-exact in round 6):
//   SGEMM_DEFAULT_Q = 320; K = 262144 -> blocks 0..817 len 320,
//   blk 818: off 261760 len 192; blk 819: off 261952 len 192.
//   Per C element: single sequential FMA chain over k within each block;
//   cross-block C += S_blk ascending; + b_loc in fp32.
// !!! The per-(blk,b,j) fmaf sequence and the K2 fp32 replay are bit-locked —
// !!! optimizations may only change load mechanics / parallel mapping.
#define QBLK 320
#define NBLK 820

__device__ __forceinline__ int blk_off(int blk) {
    if (blk <= 818) return blk * QBLK;    // 818*320 = 261760
    return 261952;                        // blk 819
}
__device__ __forceinline__ int blk_len(int blk) {
    return (blk < 818) ? 320 : 192;
}

// ---------------------------------------------------------------------------
// K1: one wave per K-block; lane = batch b (64); all 6 j-chains in registers.
// x staged through LDS in 64-k chunks, register double-buffered; storage
// XOR-swizzled (unit ^= row&7) via permuted GLOBAL addresses so both the
// ds_write and ds_read spread banks. w read with wave-uniform global loads
// (-> scalar loads, broadcast; no LDS, no per-lane VALU).
// Pipeline order (round-9 bug fix): COMMIT(c+1) BEFORE ISSUE(c+2) — r[] must
// be drained to LDS before it is reloaded.
// part layout: [b*6+j][kblk]  (transposed for K1b coalescing).
// ---------------------------------------------------------------------------
__global__ __launch_bounds__(64)
void st_block_sums(const float* __restrict__ x, const float* __restrict__ w,
                   float* __restrict__ part)
{
    __shared__ float xs[2][64 * 64];     // 2 x 16 KB = 32 KB
    const int kblk = blockIdx.x;
    const int lane = threadIdx.x;        // = batch b

    const int off    = blk_off(kblk);
    const int len    = blk_len(kblk);    // 320 or 192
    const int nchunk = len >> 6;         // 5 or 3

    // per-lane staging geometry (16 float4 per chunk): reg i covers rows
    // 4i..4i+3; within a row, 16 lanes cover 16 swizzled 16B units.
    const int srow = (lane >> 4);        // 0..3 (row within group of 4)
    const int sun  = lane & 15;          // unit 0..15

    float4 r[16];

#define K1_ISSUE(c)                                                          \
    _Pragma("unroll")                                                        \
    for (int i = 0; i < 16; ++i) {                                           \
        const int row = i * 4 + srow;                                        \
        const int kk  = ((sun ^ (row & 7)) << 2);                            \
        r[i] = *(const float4*)(x + (size_t)row * HW_ + off + (c) * 64 + kk);\
    }

#define K1_COMMIT(buf)                                                       \
    _Pragma("unroll")                                                        \
    for (int i = 0; i < 16; ++i) {                                           \
        const int row = i * 4 + srow;                                        \
        *(float4*)&xs[buf][row * 64 + sun * 4] = r[i];                       \
    }

    K1_ISSUE(0)
    K1_COMMIT(0)
    K1_ISSUE(1)        // safe even when nchunk==3: chunk 1 always exists here
                       // (min nchunk is 3)

    float a0 = 0.f, a1 = 0.f, a2 = 0.f, a3 = 0.f, a4 = 0.f, a5 = 0.f;
    const int swz = (lane & 7);

    for (int c = 0; c < nchunk; ++c) {
        __syncthreads();   // LDS visibility for cross-lane rows (cheap: 1 wave)
        const float* __restrict__ xr = xs[c & 1] + lane * 64;
        const float* __restrict__ wb = w + ((size_t)off + c * 64) * 6;
#pragma unroll
        for (int t = 0; t < 16; ++t) {
            const float4 xv = *(const float4*)(xr + ((t ^ swz) << 2));
            // w rows k..k+3 (24 floats), wave-uniform -> scalar loads
            const float4 w0 = *(const float4*)(wb + t * 24 + 0);
            const float4 w1 = *(const float4*)(wb + t * 24 + 4);
            const float4 w2 = *(const float4*)(wb + t * 24 + 8);
            const float4 w3 = *(const float4*)(wb + t * 24 + 12);
            const float4 w4 = *(const float4*)(wb + t * 24 + 16);
            const float4 w5 = *(const float4*)(wb + t * 24 + 20);
            // k+0: w0.xyzw w1.xy | k+1: w1.zw w2.xyzw
            // k+2: w3.xyzw w4.xy | k+3: w4.zw w5.xyzw
            a0 = fmaf(xv.x, w0.x, a0); a1 = fmaf(xv.x, w0.y, a1);
            a2 = fmaf(xv.x, w0.z, a2); a3 = fmaf(xv.x, w0.w, a3);
            a4 = fmaf(xv.x, w1.x, a4); a5 = fmaf(xv.x, w1.y, a5);
            a0 = fmaf(xv.y, w1.z, a0); a1 = fmaf(xv.y, w1.w, a1);
            a2 = fmaf(xv.y, w2.x, a2); a3 = fmaf(xv.y, w2.y, a3);
            a4 = fmaf(xv.y, w2.z, a4); a5 = fmaf(xv.y, w2.w, a5);
            a0 = fmaf(xv.z, w3.x, a0); a1 = fmaf(xv.z, w3.y, a1);
            a2 = fmaf(xv.z, w3.z, a2); a3 = fmaf(xv.z, w3.w, a3);
            a4 = fmaf(xv.z, w4.x, a4); a5 = fmaf(xv.z, w4.y, a5);
            a0 = fmaf(xv.w, w4.z, a0); a1 = fmaf(xv.w, w4.w, a1);
            a2 = fmaf(xv.w, w5.x, a2); a3 = fmaf(xv.w, w5.y, a3);
            a4 = fmaf(xv.w, w5.z, a4); a5 = fmaf(xv.w, w5.w, a5);
        }
        // FIX: drain r[] (chunk c+1) to LDS BEFORE reloading it with c+2.
        if (c + 1 < nchunk) { K1_COMMIT((c + 1) & 1) }
        if (c + 2 < nchunk) { K1_ISSUE(c + 2) }
    }

    float* o = part + (size_t)lane * 6 * NBLK + kblk;
    o[0 * NBLK] = a0; o[1 * NBLK] = a1; o[2 * NBLK] = a2;
    o[3 * NBLK] = a3; o[4 * NBLK] = a4; o[5 * NBLK] = a5;
}

// ---------------------------------------------------------------------------
// K1b: ordered cross-block accumulation (ascending), + b_loc in fp32.
// part[(b*6+j)][blk] contiguous per thread -> sequential streaming.
// ---------------------------------------------------------------------------
__global__ __launch_bounds__(64)
void st_theta_final(const float* __restrict__ part, const float* __restrict__ bl,
                    float* __restrict__ theta)
{
#pragma clang fp contract(off)
    const int i = blockIdx.x * 64 + threadIdx.x;   // 0..383
    const int j = i % 6;
    const float* __restrict__ p = part + (size_t)i * NBLK;
    float acc = p[0];                              // S_0 (beta=0)
    for (int blk = 1; blk < NBLK; ++blk)
        acc = acc + p[blk];
    theta[i] = acc + bl[j];
}

// window select: e[m] = v[s+m] for m=0..4, v = {A.xyzw, B.xyzw}, s in 0..3.
// Pure bit-moves (cndmask) — no FP arithmetic.
__device__ __forceinline__ void win5(const float4 A, const float4 Bv, const int s,
                                     float& e0, float& e1, float& e2,
                                     float& e3, float& e4)
{
    const bool s1 = (s & 1) != 0;
    const bool s2 = (s & 2) != 0;
    const float v0 = A.x, v1 = A.y, v2 = A.z, v3 = A.w;
    const float v4 = Bv.x, v5 = Bv.y, v6 = Bv.z, v7 = Bv.w;
    const float w0 = s1 ? v1 : v0;
    const float w1 = s1 ? v2 : v1;
    const float w2 = s1 ? v3 : v2;
    const float w3 = s1 ? v4 : v3;
    const float w4 = s1 ? v5 : v4;
    const float w5 = s1 ? v6 : v5;
    const float w6 = s1 ? v7 : v6;
    e0 = s2 ? w2 : w0;
    e1 = s2 ? w3 : w1;
    e2 = s2 ? w4 : w2;
    e3 = s2 ? w5 : w3;
    e4 = s2 ? w6 : w4;
}

// ---------------------------------------------------------------------------
// K2: bilinear sampler — faithful fp32 numpy replay downstream of theta
// (arithmetic IDENTICAL to round 6). Loads: fast path when the 4-px group is
// interior + consecutive (4 aligned float4 + window shifts, provably the same
// values); slow path = original 16 gathers otherwise.
// ---------------------------------------------------------------------------
__global__ __launch_bounds__(256)
void st_sample(const float* __restrict__ x, const float* __restrict__ theta,
               float* __restrict__ out)
{
#pragma clang fp contract(off)
    __shared__ float th[6];
    const int blk = blockIdx.x;
    const int b   = blk >> 8;          // 256 blocks per batch
    const int rem = blk & 255;
    const int yo  = rem >> 1;
    const int seg = rem & 1;

    if (threadIdx.x < 6) th[threadIdx.x] = theta[b * 6 + threadIdx.x];
    __syncthreads();

    const float t00 = th[0], t01 = th[1], t02 = th[2];
    const float t10 = th[3], t11 = th[4], t12 = th[5];

    const int xo0 = seg * 1024 + threadIdx.x * 4;
    const float* __restrict__ img = x + (size_t)b * HW_;
    const float yof = (float)yo;

    const float cx1 = t01 * yof;
    const float cy1 = t11 * yof;

    float xq[4], yq[4];
    int x0c[4], x1c[4], y0c[4], y1c[4];
    int x0raw0 = 0;

#pragma unroll
    for (int i = 0; i < 4; ++i) {
        const float xof = (float)(xo0 + i);
        const float px  = t00 * xof;
        const float sx  = px + cx1;
        xq[i] = sx + t02;
        const float py  = t10 * xof;
        const float sy  = py + cy1;
        yq[i] = sy + t12;

        const int x0 = (int)floorf(xq[i]);
        const int y0 = (int)floorf(yq[i]);
        if (i == 0) x0raw0 = x0;
        x0c[i] = min(max(x0,     0), W_ - 1);
        x1c[i] = min(max(x0 + 1, 0), W_ - 1);
        y0c[i] = min(max(y0,     0), H_ - 1);
        y1c[i] = min(max(y0 + 1, 0), H_ - 1);
    }

    const bool fast =
        (x0raw0 >= 0) &&
        (x0c[1] == x0c[0] + 1) && (x0c[2] == x0c[0] + 2) && (x0c[3] == x0c[0] + 3) &&
        (x1c[3] == x0c[3] + 1) &&
        (y0c[1] == y0c[0]) && (y0c[2] == y0c[0]) && (y0c[3] == y0c[0]) &&
        (y1c[1] == y1c[0]) && (y1c[2] == y1c[0]) && (y1c[3] == y1c[0]);

    float Ia[4], Ib[4], Ic[4], Id[4];
    if (fast) {
        const int base = x0c[0];
        const int a0   = base & ~3;
        const int s    = base & 3;
        const float* r0 = img + y0c[0] * W_ + a0;
        const float* r1 = img + y1c[0] * W_ + a0;
        const float4 A  = *(const float4*)(r0);
        const float4 Bv = *(const float4*)(r0 + 4);
        const float4 C  = *(const float4*)(r1);
        const float4 D  = *(const float4*)(r1 + 4);
        float e0, e1, e2, e3, e4;
        win5(A, Bv, s, e0, e1, e2, e3, e4);
        Ia[0] = e0; Ia[1] = e1; Ia[2] = e2; Ia[3] = e3;
        Ic[0] = e1; Ic[1] = e2; Ic[2] = e3; Ic[3] = e4;
        win5(C, D, s, e0, e1, e2, e3, e4);
        Ib[0] = e0; Ib[1] = e1; Ib[2] = e2; Ib[3] = e3;
        Id[0] = e1; Id[1] = e2; Id[2] = e3; Id[3] = e4;
    } else {
#pragma unroll
        for (int i = 0; i < 4; ++i) {
            const float* r0 = img + y0c[i] * W_;
            const float* r1 = img + y1c[i] * W_;
            Ia[i] = r0[x0c[i]];
            Ib[i] = r1[x0c[i]];
            Ic[i] = r0[x1c[i]];
            Id[i] = r1[x1c[i]];
        }
    }

    nfloat4 o;
#pragma unroll
    for (int i = 0; i < 4; ++i) {
        const float x0f = (float)x0c[i], x1f = (float)x1c[i];
        const float y0f = (float)y0c[i], y1f = (float)y1c[i];

        const float gx = x1f - xq[i];
        const float fx = xq[i] - x0f;
        const float gy = y1f - yq[i];
        const float fy = yq[i] - y0f;

        const float wa = gx * gy;
        const float wb = gx * fy;
        const float wc = fx * gy;
        const float wd = fx * fy;

        const float pa = wa * Ia[i];
        const float pb = wb * Ib[i];
        const float s1 = pa + pb;
        const float pc = wc * Ic[i];
        const float s2 = s1 + pc;
        const float pd = wd * Id[i];
        o[i] = s2 + pd;
    }

    const size_t oidx = ((size_t)b * OH_ + yo) * OW_ + xo0;
    __builtin_nontemporal_store(o, (nfloat4*)(out + oidx));
}

extern "C" void kernel_launch(void* const* d_in, const int* in_sizes, int n_in,
                              void* d_out, int out_size, void* d_ws, size_t ws_size,
                              hipStream_t stream)
{
    const float* x  = (const float*)d_in[0];
    const float* w  = (const float*)d_in[1];
    const float* bl = (const float*)d_in[2];
    float* out = (float*)d_out;

    // d_out doubles as the 1.26 MB block-sum scratch (384*820 floats), fully
    // consumed by st_theta_final before st_sample overwrites every element.
    float* part  = (float*)d_out;
    float* theta = (float*)d_ws;    // 384 floats

    st_block_sums<<<NBLK, 64, 0, stream>>>(x, w, part);
    st_theta_final<<<6, 64, 0, stream>>>(part, bl, theta);
    st_sample<<<B_ * OH_ * 2, 256, 0, stream>>>(x, theta, out);
}